// Round 1
// baseline (78.664 us; speedup 1.0000x reference)
//
#include <hip/hip_runtime.h>
#include <math.h>

#define N_ANCH 10647
#define N_GT   2048
#define N_OUTC 85
#define PRED_ELEMS (N_ANCH * N_OUTC)   // 904995
#define PRED_V4    (PRED_ELEMS / 4)    // 226248 (3 tail floats)
#define GT_CHUNK   128
#define A_CHUNK    128

struct WS {
    unsigned long long akey[N_ANCH];   // per-anchor packed (iou_bits<<32)|~gt_idx
    unsigned long long gkey[N_GT];     // per-GT packed (iou_bits<<32)|~anchor_idx
    unsigned int flags[N_ANCH];        // is_gt_max scatter
    int poslist[128];
    int neglist[256];
    int counts[2];                     // n_pos_final, n_neg_final
    float part_a[128];                 // box + conf_obj partials (both /n_pos)
    float part_cls[128];
    float part_neg[2];
};

__device__ __forceinline__ float bce(float x, float t) {
    // matches: max(x,0) - x*t + log1p(exp(-|x|))
    return fmaxf(x, 0.0f) - x * t + log1pf(expf(-fabsf(x)));
}

// ---------------- K0: copy pred -> out, zero keys/flags ----------------
__global__ __launch_bounds__(256) void k_prep(const float* __restrict__ pred,
                                              float* __restrict__ out,
                                              WS* __restrict__ ws) {
    int idx = blockIdx.x * 256 + threadIdx.x;
    if (idx < PRED_V4)
        ((float4*)out)[idx] = ((const float4*)pred)[idx];
    if (idx == 0) {
        out[PRED_ELEMS - 3] = pred[PRED_ELEMS - 3];
        out[PRED_ELEMS - 2] = pred[PRED_ELEMS - 2];
        out[PRED_ELEMS - 1] = pred[PRED_ELEMS - 1];
    }
    if (idx < N_ANCH) { ws->akey[idx] = 0ull; ws->flags[idx] = 0u; }
    if (idx < N_GT)   { ws->gkey[idx] = 0ull; }
}

// ---------------- KA: per-anchor max/argmax over GTs ----------------
// grid (ceil(N_ANCH/256), N_GT/GT_CHUNK), block 256. Thread = anchor.
__global__ __launch_bounds__(256) void k_amax(const float* __restrict__ priors,
                                              const float* __restrict__ gtb,
                                              WS* __restrict__ ws) {
    __shared__ float4 sb[GT_CHUNK];
    __shared__ float  sba[GT_CHUNK];
    int tx = threadIdx.x;
    int jbase = blockIdx.y * GT_CHUNK;
    if (tx < GT_CHUNK) {
        int j = jbase + tx;
        float cx = gtb[j*4+0], cy = gtb[j*4+1], w = gtb[j*4+2], h = gtb[j*4+3];
        float4 c = make_float4(cx - w*0.5f, cy - h*0.5f, cx + w*0.5f, cy + h*0.5f);
        sb[tx] = c;
        sba[tx] = (c.z - c.x) * (c.w - c.y);
    }
    __syncthreads();
    int i = blockIdx.x * 256 + tx;
    float4 a = make_float4(0.f, 0.f, 0.f, 0.f);
    float aa = 0.f;
    if (i < N_ANCH) {
        float cx = priors[i*N_OUTC+0], cy = priors[i*N_OUTC+1];
        float w  = priors[i*N_OUTC+2], h  = priors[i*N_OUTC+3];
        a = make_float4(cx - w*0.5f, cy - h*0.5f, cx + w*0.5f, cy + h*0.5f);
        aa = (a.z - a.x) * (a.w - a.y);
    }
    unsigned long long best = 0ull;
#pragma unroll 4
    for (int jj = 0; jj < GT_CHUNK; ++jj) {
        float4 b = sb[jj]; float ab = sba[jj];
        float lx = fmaxf(a.x, b.x), ly = fmaxf(a.y, b.y);
        float rx = fminf(a.z, b.z), ry = fminf(a.w, b.w);
        float ww = fmaxf(rx - lx, 0.0f), hh = fmaxf(ry - ly, 0.0f);
        float inter = ww * hh;
        float uni = (aa + ab) - inter;
        float iou = inter / uni;
        unsigned long long key =
            ((unsigned long long)__float_as_uint(iou) << 32) |
            (unsigned)(~(unsigned)(jbase + jj));
        best = (key > best) ? key : best;
    }
    if (i < N_ANCH) atomicMax(&ws->akey[i], best);
}

// ---------------- KB: per-GT argmax over anchors ----------------
// grid (N_GT/256, ceil(N_ANCH/A_CHUNK)), block 256. Thread = GT.
__global__ __launch_bounds__(256) void k_gmax(const float* __restrict__ priors,
                                              const float* __restrict__ gtb,
                                              WS* __restrict__ ws) {
    __shared__ float4 sa[A_CHUNK];
    __shared__ float  saa[A_CHUNK];
    int tx = threadIdx.x;
    int ibase = blockIdx.y * A_CHUNK;
    if (tx < A_CHUNK) {
        int i = ibase + tx;
        float4 c = make_float4(0.f, 0.f, 0.f, 0.f);
        float ar = 0.f;
        if (i < N_ANCH) {
            float cx = priors[i*N_OUTC+0], cy = priors[i*N_OUTC+1];
            float w  = priors[i*N_OUTC+2], h  = priors[i*N_OUTC+3];
            c = make_float4(cx - w*0.5f, cy - h*0.5f, cx + w*0.5f, cy + h*0.5f);
            ar = (c.z - c.x) * (c.w - c.y);
        }
        sa[tx] = c; saa[tx] = ar;
    }
    __syncthreads();
    int j = blockIdx.x * 256 + tx;
    float cx = gtb[j*4+0], cy = gtb[j*4+1], w = gtb[j*4+2], h = gtb[j*4+3];
    float4 b = make_float4(cx - w*0.5f, cy - h*0.5f, cx + w*0.5f, cy + h*0.5f);
    float ab = (b.z - b.x) * (b.w - b.y);
    unsigned long long best = 0ull;
#pragma unroll 4
    for (int ii = 0; ii < A_CHUNK; ++ii) {
        float4 a = sa[ii]; float aa = saa[ii];
        float lx = fmaxf(a.x, b.x), ly = fmaxf(a.y, b.y);
        float rx = fminf(a.z, b.z), ry = fminf(a.w, b.w);
        float ww = fmaxf(rx - lx, 0.0f), hh = fmaxf(ry - ly, 0.0f);
        float inter = ww * hh;
        float uni = (aa + ab) - inter;
        float iou = inter / uni;
        // degenerate (i >= N_ANCH) boxes give iou=0 with a larger fake index
        // -> key strictly below any real candidate; never wins.
        unsigned long long key =
            ((unsigned long long)__float_as_uint(iou) << 32) |
            (unsigned)(~(unsigned)(ibase + ii));
        best = (key > best) ? key : best;
    }
    atomicMax(&ws->gkey[j], best);
}

// ---------------- KL: labels, demote-first scans, compact lists ----------------
__global__ __launch_bounds__(1024) void k_labels(WS* __restrict__ ws) {
    __shared__ int w1[16], w2[16];
    int tid = threadIdx.x, lane = tid & 63, wid = tid >> 6;

    // scatter is_gt_max flags
    for (int j = tid; j < N_GT; j += 1024) {
        unsigned ai = ~(unsigned)(ws->gkey[j]);
        ws->flags[ai] = 1u;
    }
    __syncthreads();

    const int NCH = (N_ANCH + 1023) / 1024;  // 11
    // pass 1: counts
    int cp = 0, cn = 0;
    for (int c = 0; c < NCH; ++c) {
        int i = c * 1024 + tid;
        if (i < N_ANCH) {
            float amax = __uint_as_float((unsigned)(ws->akey[i] >> 32));
            int lab = (amax < 0.3f) ? 0 : ((amax >= 0.7f || ws->flags[i]) ? 1 : -1);
            cp += (lab == 1); cn += (lab == 0);
        }
    }
    for (int o = 32; o; o >>= 1) { cp += __shfl_down(cp, o); cn += __shfl_down(cn, o); }
    if (lane == 0) { w1[wid] = cp; w2[wid] = cn; }
    __syncthreads();
    int npa = 0, nna = 0;
    for (int w = 0; w < 16; ++w) { npa += w1[w]; nna += w2[w]; }
    __syncthreads();

    int excess_pos = (npa > 128) ? (npa - 128) : 0;
    int n_pos_f = npa - excess_pos;
    int n_neg_req = 256 - n_pos_f;
    int excess_neg = (nna > n_neg_req) ? (nna - n_neg_req) : 0;
    int n_neg_f = nna - excess_neg;

    // pass 2: global inclusive ranks -> demote first `excess`, compact the rest
    int run_p = 0, run_n = 0;
    for (int c = 0; c < NCH; ++c) {
        int i = c * 1024 + tid;
        int lab = -2;
        if (i < N_ANCH) {
            float amax = __uint_as_float((unsigned)(ws->akey[i] >> 32));
            lab = (amax < 0.3f) ? 0 : ((amax >= 0.7f || ws->flags[i]) ? 1 : -1);
        }
        bool f1 = (lab == 1), f0 = (lab == 0);
        unsigned long long b1 = __ballot(f1), b0 = __ballot(f0);
        unsigned long long pm = (2ull << lane) - 1ull;  // inclusive mask (lane 63 ok)
        int r1 = __popcll(b1 & pm), r0 = __popcll(b0 & pm);
        if (lane == 0) { w1[wid] = __popcll(b1); w2[wid] = __popcll(b0); }
        __syncthreads();
        int p1 = 0, t1 = 0, p0 = 0, t0 = 0;
        for (int w = 0; w < 16; ++w) {
            int v1 = w1[w], v0 = w2[w];
            t1 += v1; t0 += v0;
            if (w < wid) { p1 += v1; p0 += v0; }
        }
        if (f1) {
            int cum = run_p + p1 + r1;               // inclusive cumsum, 1-based
            if (cum > excess_pos) ws->poslist[cum - excess_pos - 1] = i;
        }
        if (f0) {
            int cum = run_n + p0 + r0;
            if (cum > excess_neg) ws->neglist[cum - excess_neg - 1] = i;
        }
        run_p += t1; run_n += t0;
        __syncthreads();
    }
    if (tid == 0) { ws->counts[0] = n_pos_f; ws->counts[1] = n_neg_f; }
}

// ---------------- KF: per-block loss partials ----------------
// blocks 0..127: one pos anchor each (thread = column 0..84)
// blocks 128..129: neg conf terms, 128 each
__global__ __launch_bounds__(128) void k_loss(const float* __restrict__ pred,
                                              const float* __restrict__ gtb,
                                              const int* __restrict__ gtl,
                                              WS* __restrict__ ws) {
    __shared__ float r[4];
    int b = blockIdx.x, t = threadIdx.x, lane = t & 63, wid = t >> 6;
    if (b < 128) {
        int npf = ws->counts[0];
        float at = 0.f, ct = 0.f;
        if (b < npf && t < N_OUTC) {
            int i = ws->poslist[b];
            unsigned am = ~(unsigned)(ws->akey[i]);
            float p = pred[i * N_OUTC + t];
            if (t < 4) {
                float d = p - gtb[am * 4 + t];
                at = d * d;
            } else if (t == 4) {
                at = bce(p, 1.0f);
            } else {
                int cls = gtl[am] + 5;
                ct = bce(p, (t == cls) ? 1.0f : 0.0f);
            }
        }
        for (int o = 32; o; o >>= 1) { at += __shfl_down(at, o); ct += __shfl_down(ct, o); }
        if (lane == 0) { r[wid] = at; r[2 + wid] = ct; }
        __syncthreads();
        if (t == 0) { ws->part_a[b] = r[0] + r[1]; ws->part_cls[b] = r[2] + r[3]; }
    } else {
        int nnf = ws->counts[1];
        int idx = (b - 128) * 128 + t;
        float v = 0.f;
        if (idx < nnf) {
            int i = ws->neglist[idx];
            v = bce(pred[i * N_OUTC + 4], 0.0f);
        }
        for (int o = 32; o; o >>= 1) v += __shfl_down(v, o);
        if (lane == 0) r[wid] = v;
        __syncthreads();
        if (t == 0) ws->part_neg[b - 128] = r[0] + r[1];
    }
}

// ---------------- KG: finalize scalar loss ----------------
__global__ __launch_bounds__(128) void k_final(WS* __restrict__ ws, float* __restrict__ out) {
    __shared__ float r[4];
    int t = threadIdx.x, lane = t & 63, wid = t >> 6;
    float A = ws->part_a[t], C = ws->part_cls[t];
    for (int o = 32; o; o >>= 1) { A += __shfl_down(A, o); C += __shfl_down(C, o); }
    if (lane == 0) { r[wid] = A; r[2 + wid] = C; }
    __syncthreads();
    if (t == 0) {
        float As = r[0] + r[1], Cs = r[2] + r[3];
        float CN = ws->part_neg[0] + ws->part_neg[1];
        float np = fmaxf((float)ws->counts[0], 1.0f);
        float nn = fmaxf((float)ws->counts[1], 1.0f);
        out[PRED_ELEMS] = As / np + CN / nn + Cs / (np * 80.0f);
    }
}

extern "C" void kernel_launch(void* const* d_in, const int* in_sizes, int n_in,
                              void* d_out, int out_size, void* d_ws, size_t ws_size,
                              hipStream_t stream) {
    const float* pred   = (const float*)d_in[0];
    const float* gtb    = (const float*)d_in[1];
    const int*   gtl    = (const int*)d_in[2];
    const float* priors = (const float*)d_in[3];
    float* out = (float*)d_out;
    WS* ws = (WS*)d_ws;

    k_prep<<<dim3((PRED_V4 + 255) / 256), 256, 0, stream>>>(pred, out, ws);
    k_amax<<<dim3((N_ANCH + 255) / 256, N_GT / GT_CHUNK), 256, 0, stream>>>(priors, gtb, ws);
    k_gmax<<<dim3(N_GT / 256, (N_ANCH + A_CHUNK - 1) / A_CHUNK), 256, 0, stream>>>(priors, gtb, ws);
    k_labels<<<1, 1024, 0, stream>>>(ws);
    k_loss<<<130, 128, 0, stream>>>(pred, gtb, gtl, ws);
    k_final<<<1, 128, 0, stream>>>(ws, out);
}